// Round 14
// baseline (157.602 us; speedup 1.0000x reference)
//
#include <hip/hip_runtime.h>

#define N_ATOM 10000
#define N_EDGE 40000
#define DD 64
#define BOND_DIM 10
#define EPS_BN 1e-6f
#define EPS_SM 1e-8f
#define GA 8     // atoms per GRU block

typedef __attribute__((ext_vector_type(8))) short short8;
typedef __attribute__((ext_vector_type(2))) float float2v;
typedef __attribute__((ext_vector_type(4))) float float4v;
typedef __attribute__((ext_vector_type(16))) float float16v;
typedef unsigned int u32;

// ---- workspace layout (dword indices) ----
constexpr size_t OFF_AFRAG   = 0;        // 32768 dw: [d][chunk][lane] x4dw  W'^T A-frags (32x32x16)
constexpr size_t OFF_ATTFRAG = 32768;    // 2048 dw: 8 (fc*2+kh) x 64 lanes x 4 dw (16x16x32 B-frags)
constexpr size_t OFF_ATTB    = 34816;    // 64
constexpr size_t OFF_WIHT    = 34880;    // 12288 WihT[d*192+t]
constexpr size_t OFF_WHHT    = 47168;    // 12288
constexpr size_t OFF_SALIGN  = 59456;    // 10000: dot(atom[a], alignW[0:64])
constexpr size_t OFF_DENOM   = 69456;    // N_ATOM
constexpr size_t OFF_CTX     = 79456;    // N_ATOM*DD
// total 719,456 dwords ~= 2.88 MB

__device__ __forceinline__ unsigned short f2bf(float x) {
    u32 u = __float_as_uint(x);
    u32 r = u + 0x7FFFu + ((u >> 16) & 1u);   // RNE
    return (unsigned short)(r >> 16);
}

// ---------- kernel 0: fold BN, build MFMA fragments, transposes, salign, zero accumulators ----------
__global__ void fold_kernel(const float* atom, const float* alignW,
                            const float* enc_W, const float* enc_b,
                            const float* g1, const float* b1,
                            const float* m1, const float* v1,
                            const float* att_W, const float* att_b,
                            const float* g2, const float* b2v,
                            const float* m2, const float* v2,
                            const float* Wih, const float* Whh,
                            float* ws) {
    u32* wsu = (u32*)ws;
    size_t i = (size_t)blockIdx.x * 256 + threadIdx.x;
    if (i < 8192) {
        // W'^T A-fragment for 32x32x16: m = l&31 -> enc col c = d*64 + ch*32 + m ; k = 8*(l>>5)+j
        int d = i >> 7, rem = i & 127;
        int ch = rem >> 6, l = rem & 63;
        int c = d * 64 + ch * 32 + (l & 31);
        int kb = 8 * (l >> 5);
        float s = g1[c] * rsqrtf(v1[c] + EPS_BN);
        float bias = enc_b[c] * s + b1[c] - m1[c] * s;
        unsigned short h[8];
#pragma unroll
        for (int j = 0; j < 8; j++) {
            int k = kb + j;
            float v = (k < BOND_DIM) ? enc_W[c * BOND_DIM + k] * s
                                     : ((k == BOND_DIM) ? bias : 0.f);
            h[j] = f2bf(v);
        }
#pragma unroll
        for (int m = 0; m < 4; m++)
            wsu[OFF_AFRAG + i * 4 + m] = (u32)h[2 * m] | ((u32)h[2 * m + 1] << 16);
    } else if (i < 8704) {
        // attention B-fragment (16x16x32), round-8-verified layout
        int idx = i - 8192;
        int l = idx & 63, fckh = idx >> 6;
        int fc = fckh >> 1, kh = fckh & 1, q = l >> 4;
        int n = (fc << 4) + (l & 15);
        float s = g2[n] * rsqrtf(v2[n] + EPS_BN);
        unsigned short h[8];
#pragma unroll
        for (int j = 0; j < 8; j++) {
            int k = 32 * kh + 8 * q + j;
            h[j] = f2bf(att_W[n * DD + k] * s);
        }
#pragma unroll
        for (int m = 0; m < 4; m++)
            wsu[OFF_ATTFRAG + (size_t)idx * 4 + m] = (u32)h[2 * m] | ((u32)h[2 * m + 1] << 16);
    } else if (i < 8768) {
        int f = i - 8704;
        float s = g2[f] * rsqrtf(v2[f] + EPS_BN);
        ws[OFF_ATTB + f] = att_b[f] * s + b2v[f] - m2[f] * s;
    } else if (i < 21056) {
        int j = i - 8768;
        int d = j / 192, t = j % 192;
        ws[OFF_WIHT + j] = Wih[t * DD + d];
    } else if (i < 33344) {
        int j = i - 21056;
        int d = j / 192, t = j % 192;
        ws[OFF_WHHT + j] = Whh[t * DD + d];
    } else if (i < 43344) {
        // salign[a] = dot(atom[a], alignW[0:64])
        int a = i - 33344;
        const float4* ar = (const float4*)(atom + (size_t)a * DD);
        const float4* aw = (const float4*)alignW;
        float s = 0.f;
#pragma unroll
        for (int qq = 0; qq < 16; qq++) {
            float4 x = ar[qq], w = aw[qq];
            s += x.x * w.x + x.y * w.y + x.z * w.z + x.w * w.w;
        }
        ws[OFF_SALIGN + a] = s;
    } else {
        size_t z = i - 43344;
        if (z < (size_t)N_ATOM + (size_t)N_ATOM * DD) ws[OFF_DENOM + z] = 0.f;
    }
}

// ---------- kernel 1: transposed-MFMA edge pipeline, 4-way d-split ----------
// 256 threads = 4 waves; 32 edges/block (1250 blocks); wave h owns d-quarter.
// W' loads batched 16-at-a-time into a register array (8 d-iters per group):
// forces back-to-back global_load_dwordx4 with staggered vmcnt -> L2 latency
// exposed once per group instead of once per load.
__global__ __launch_bounds__(256) void edge_kernel(
    const float* atom, const int* bidx, const float* bond,
    const float* alignW, const float* alignb,
    const float* ws, float* denom, float* ctx) {
    __shared__ float s_bond[32][BOND_DIM];
    __shared__ float s_anbr[32][65];
    __shared__ float s_nbp[2][32][65];
    __shared__ float s_ex[32];
    __shared__ int   s_tgt[32];

    const int t = threadIdx.x;
    const int lane = t & 63;
    const int h = t >> 6;        // wave = d-quarter
    const int e0 = blockIdx.x * 32;

    // ---- staging ----
    for (int idx = t; idx < 32 * BOND_DIM; idx += 256)
        s_bond[idx / BOND_DIM][idx % BOND_DIM] = bond[(size_t)e0 * BOND_DIM + idx];
    if (t < 32) s_tgt[t] = bidx[2 * (e0 + t)];
    for (int e = h; e < 32; e += 4) {
        int nbr = bidx[2 * (e0 + e) + 1];
        s_anbr[e][lane] = atom[(size_t)nbr * DD + lane];
    }
    __syncthreads();

    // stationary bond B-fragment: B[k=8*(lane>>5)+j][n=lane&31]
    const int eb = lane & 31;
    const int kb = 8 * (lane >> 5);
    short8 bfrag;
#pragma unroll
    for (int j = 0; j < 8; j++) {
        int k = kb + j;
        unsigned short hh = 0;
        if (k < BOND_DIM) hh = f2bf(s_bond[eb][k]);
        else if (k == BOND_DIM) hh = 0x3F80u;   // 1.0 (bias slot)
        bfrag[j] = (short)hh;
    }

    const int d0 = 16 * h;
    const short8* aw = (const short8*)((const u32*)ws + OFF_AFRAG) + ((size_t)(d0 * 2) * 64 + lane);
    const float16v zero16 = {};
    const float2v zero2 = {0.f, 0.f};
    float2v nb0[8] = {}, nb1[8] = {};

    // main loop: 2 groups x 8 d-iters; 16 loads batched up-front per group
#pragma unroll
    for (int grp = 0; grp < 2; grp++) {
        short8 a[16];
#pragma unroll
        for (int j = 0; j < 16; j++)
            a[j] = aw[(size_t)(grp * 16 + j) * 64];
#pragma unroll
        for (int it = 0; it < 8; it++) {
            int d = d0 + grp * 8 + it;
            float av = s_anbr[eb][d];
            float2v av2 = {av, av};
            float16v enc0 = __builtin_amdgcn_mfma_f32_32x32x16_bf16(a[2 * it], bfrag, zero16, 0, 0, 0);
            float16v enc1 = __builtin_amdgcn_mfma_f32_32x32x16_bf16(a[2 * it + 1], bfrag, zero16, 0, 0, 0);
#pragma unroll
            for (int r = 0; r < 8; r++) {
                float2v e0v = {enc0[2 * r], enc0[2 * r + 1]};
                float2v e1v = {enc1[2 * r], enc1[2 * r + 1]};
                e0v = __builtin_elementwise_max(e0v, zero2);
                e1v = __builtin_elementwise_max(e1v, zero2);
                nb0[r] += av2 * e0v;    // contracts to v_pk_fma_f32
                nb1[r] += av2 * e1v;
            }
        }
    }

    // partial nb reduction: waves 0,1 write buffers; waves 2,3 add in place.
    // element e=2r,2r+1 -> f = (e&3)+8*(e>>2)+fro (m74/m101 layout)
    const int fro = 4 * (lane >> 5);
    if (h < 2) {
#pragma unroll
        for (int r = 0; r < 8; r++) {
            int e = 2 * r;
            int f = (e & 3) + 8 * (e >> 2) + fro;
            s_nbp[h][eb][f] = nb0[r].x;
            s_nbp[h][eb][f + 1] = nb0[r].y;
            s_nbp[h][eb][32 + f] = nb1[r].x;
            s_nbp[h][eb][32 + f + 1] = nb1[r].y;
        }
    }
    __syncthreads();
    if (h >= 2) {
#pragma unroll
        for (int r = 0; r < 8; r++) {
            int e = 2 * r;
            int f = (e & 3) + 8 * (e >> 2) + fro;
            s_nbp[h - 2][eb][f] += nb0[r].x;
            s_nbp[h - 2][eb][f + 1] += nb0[r].y;
            s_nbp[h - 2][eb][32 + f] += nb1[r].x;
            s_nbp[h - 2][eb][32 + f + 1] += nb1[r].y;
        }
    }
    __syncthreads();

    // ---- phase B: split across 4 waves; subtile es = (h&1)*16 ----
    const int es = (h & 1) * 16;
    const int q = lane >> 4;
    const int r16 = lane & 15;
    float4v att[4];

    if (h < 2) {
        // GEMM2: atend = nb @ attWT (16x16x32, round-8-verified layouts)
        short8 na[2];
#pragma unroll
        for (int kh = 0; kh < 2; kh++)
#pragma unroll
            for (int j = 0; j < 8; j++) {
                int k = 32 * kh + 8 * q + j;
                na[kh][j] = (short)f2bf(s_nbp[0][es + r16][k] + s_nbp[1][es + r16][k]);
            }
        const short8* battfrag = (const short8*)((const u32*)ws + OFF_ATTFRAG);
        const float4v zero4 = {0.f, 0.f, 0.f, 0.f};
#pragma unroll
        for (int fc = 0; fc < 4; fc++) {
            att[fc] = __builtin_amdgcn_mfma_f32_16x16x32_bf16(na[0], battfrag[(fc * 2 + 0) * 64 + lane], zero4, 0, 0, 0);
            att[fc] = __builtin_amdgcn_mfma_f32_16x16x32_bf16(na[1], battfrag[(fc * 2 + 1) * 64 + lane], att[fc], 0, 0, 0);
            float ab = ws[OFF_ATTB + fc * 16 + r16];
#pragma unroll
            for (int r = 0; r < 4; r++) att[fc][r] += ab;
        }
    } else {
        // score + exp + denom atomics; atom-part precomputed in salign
        const float* salign = ws + OFF_SALIGN;
        const float aw2 = alignW[64 + lane];
        const float alb = alignb[0];
#pragma unroll 4
        for (int e = 0; e < 16; e++) {
            int le = es + e;
            int tgt = s_tgt[le];
            float v = (s_nbp[0][le][lane] + s_nbp[1][le][lane]) * aw2;
#pragma unroll
            for (int off = 32; off > 0; off >>= 1) v += __shfl_xor(v, off);
            float sc = salign[tgt] + v + alb;
            sc = sc > 0.f ? sc : 0.01f * sc;   // leaky_relu slope 0.01
            float ex = expf(sc);               // no max-shift: ratio identity, scores O(1)
            if (lane == 0) {
                s_ex[le] = ex;
                atomicAdd(&denom[tgt], ex);
            }
        }
    }
    __syncthreads();

    if (h < 2) {
        // ctx segment-sum atomics (C-layout: e = es+4q+r, f = fc*16+r16)
#pragma unroll
        for (int r = 0; r < 4; r++) {
            int le = es + 4 * q + r;
            float exr = s_ex[le];
            int tg = s_tgt[le];
#pragma unroll
            for (int fc = 0; fc < 4; fc++)
                atomicAdd(&ctx[(size_t)tg * DD + fc * 16 + r16], exr * att[fc][r]);
        }
    }
}

// ---------- kernel 2: context finalize (elu) + GRU cell, transposed weights ----------
__global__ __launch_bounds__(192) void gru_kernel(
    const float* atom, const float* ws, const float* denom, const float* ctx,
    const float* bih, const float* bhh, float* out) {
    __shared__ float sctx[GA][DD];
    __shared__ float satom[GA][DD];
    __shared__ float sgi[GA][192];
    __shared__ float sgh[GA][192];
    const int a0 = blockIdx.x * GA;
    const int t = threadIdx.x;

    for (int idx = t; idx < GA * DD; idx += 192) {
        int a = idx >> 6, f = idx & 63;
        float c = ctx[(size_t)(a0 + a) * DD + f] / (denom[a0 + a] + EPS_SM);
        sctx[a][f] = c > 0.f ? c : expm1f(c);  // elu
        satom[a][f] = atom[(size_t)(a0 + a) * DD + f];
    }
    __syncthreads();

    const float* wiht = ws + OFF_WIHT;
    const float* whht = ws + OFF_WHHT;
    float gi[GA], gh[GA];
    const float bi = bih[t], bh = bhh[t];
#pragma unroll
    for (int a = 0; a < GA; a++) { gi[a] = bi; gh[a] = bh; }
#pragma unroll 4
    for (int d = 0; d < DD; d++) {
        float wi = wiht[d * 192 + t];
        float wh = whht[d * 192 + t];
#pragma unroll
        for (int a = 0; a < GA; a++) {
            gi[a] = fmaf(wi, sctx[a][d], gi[a]);
            gh[a] = fmaf(wh, satom[a][d], gh[a]);
        }
    }
#pragma unroll
    for (int a = 0; a < GA; a++) { sgi[a][t] = gi[a]; sgh[a][t] = gh[a]; }
    __syncthreads();

    for (int idx = t; idx < GA * DD; idx += 192) {
        int a = idx >> 6, f = idx & 63;
        float r = 1.f / (1.f + expf(-(sgi[a][f] + sgh[a][f])));
        float z = 1.f / (1.f + expf(-(sgi[a][64 + f] + sgh[a][64 + f])));
        float n = tanhf(sgi[a][128 + f] + r * sgh[a][128 + f]);
        out[(size_t)(a0 + a) * DD + f] = (1.f - z) * n + z * satom[a][f];
    }
}

extern "C" void kernel_launch(void* const* d_in, const int* in_sizes, int n_in,
                              void* d_out, int out_size, void* d_ws, size_t ws_size,
                              hipStream_t stream) {
    const float* atom   = (const float*)d_in[0];
    const int*   bidx   = (const int*)d_in[1];
    const float* bond   = (const float*)d_in[2];
    const float* enc_W  = (const float*)d_in[3];
    const float* enc_b  = (const float*)d_in[4];
    const float* bn1_g  = (const float*)d_in[5];
    const float* bn1_b  = (const float*)d_in[6];
    const float* bn1_m  = (const float*)d_in[7];
    const float* bn1_v  = (const float*)d_in[8];
    const float* alignW = (const float*)d_in[9];
    const float* alignb = (const float*)d_in[10];
    const float* att_W  = (const float*)d_in[11];
    const float* att_b  = (const float*)d_in[12];
    const float* bn2_g  = (const float*)d_in[13];
    const float* bn2_b  = (const float*)d_in[14];
    const float* bn2_m  = (const float*)d_in[15];
    const float* bn2_v  = (const float*)d_in[16];
    const float* gWih   = (const float*)d_in[17];
    const float* gWhh   = (const float*)d_in[18];
    const float* gbih   = (const float*)d_in[19];
    const float* gbhh   = (const float*)d_in[20];

    float* ws  = (float*)d_ws;
    float* out = (float*)d_out;

    fold_kernel<<<2709, 256, 0, stream>>>(atom, alignW,
                                          enc_W, enc_b, bn1_g, bn1_b, bn1_m, bn1_v,
                                          att_W, att_b, bn2_g, bn2_b, bn2_m, bn2_v,
                                          gWih, gWhh, ws);

    edge_kernel<<<N_EDGE / 32, 256, 0, stream>>>(
        atom, bidx, bond, alignW, alignb, ws,
        ws + OFF_DENOM, ws + OFF_CTX);

    gru_kernel<<<N_ATOM / GA, 192, 0, stream>>>(atom, ws, ws + OFF_DENOM, ws + OFF_CTX,
                                                gbih, gbhh, out);
}

// Round 15
// 144.599 us; speedup vs baseline: 1.0899x; 1.0899x over previous
//
#include <hip/hip_runtime.h>

#define N_ATOM 10000
#define N_EDGE 40000
#define DD 64
#define BOND_DIM 10
#define EPS_BN 1e-6f
#define EPS_SM 1e-8f
#define GA 8     // atoms per GRU block

typedef __attribute__((ext_vector_type(8))) short short8;
typedef __attribute__((ext_vector_type(2))) float float2v;
typedef __attribute__((ext_vector_type(4))) float float4v;
typedef __attribute__((ext_vector_type(16))) float float16v;
typedef unsigned int u32;

// ---- workspace layout (dword indices) ----
constexpr size_t OFF_AFRAG   = 0;        // 32768 dw: [d][chunk][lane] x4dw  W'^T A-frags (32x32x16)
constexpr size_t OFF_ATTFRAG = 32768;    // 2048 dw: 8 (fc*2+kh) x 64 lanes x 4 dw (16x16x32 B-frags)
constexpr size_t OFF_ATTB    = 34816;    // 64
constexpr size_t OFF_WIHT    = 34880;    // 12288 WihT[d*192+t]
constexpr size_t OFF_WHHT    = 47168;    // 12288
constexpr size_t OFF_SALIGN  = 59456;    // 10000: dot(atom[a], alignW[0:64])
constexpr size_t OFF_DENOM   = 69456;    // N_ATOM
constexpr size_t OFF_CTX     = 79456;    // N_ATOM*DD
// total 719,456 dwords ~= 2.88 MB

__device__ __forceinline__ unsigned short f2bf(float x) {
    u32 u = __float_as_uint(x);
    u32 r = u + 0x7FFFu + ((u >> 16) & 1u);   // RNE
    return (unsigned short)(r >> 16);
}

// ---------- kernel 0: fold BN, build MFMA fragments, transposes, salign, zero accumulators ----------
__global__ void fold_kernel(const float* atom, const float* alignW,
                            const float* enc_W, const float* enc_b,
                            const float* g1, const float* b1,
                            const float* m1, const float* v1,
                            const float* att_W, const float* att_b,
                            const float* g2, const float* b2v,
                            const float* m2, const float* v2,
                            const float* Wih, const float* Whh,
                            float* ws) {
    u32* wsu = (u32*)ws;
    size_t i = (size_t)blockIdx.x * 256 + threadIdx.x;
    if (i < 8192) {
        // W'^T A-fragment for 32x32x16: m = l&31 -> enc col c = d*64 + ch*32 + m ; k = 8*(l>>5)+j
        int d = i >> 7, rem = i & 127;
        int ch = rem >> 6, l = rem & 63;
        int c = d * 64 + ch * 32 + (l & 31);
        int kb = 8 * (l >> 5);
        float s = g1[c] * rsqrtf(v1[c] + EPS_BN);
        float bias = enc_b[c] * s + b1[c] - m1[c] * s;
        unsigned short h[8];
#pragma unroll
        for (int j = 0; j < 8; j++) {
            int k = kb + j;
            float v = (k < BOND_DIM) ? enc_W[c * BOND_DIM + k] * s
                                     : ((k == BOND_DIM) ? bias : 0.f);
            h[j] = f2bf(v);
        }
#pragma unroll
        for (int m = 0; m < 4; m++)
            wsu[OFF_AFRAG + i * 4 + m] = (u32)h[2 * m] | ((u32)h[2 * m + 1] << 16);
    } else if (i < 8704) {
        // attention B-fragment (16x16x32), round-8-verified layout
        int idx = i - 8192;
        int l = idx & 63, fckh = idx >> 6;
        int fc = fckh >> 1, kh = fckh & 1, q = l >> 4;
        int n = (fc << 4) + (l & 15);
        float s = g2[n] * rsqrtf(v2[n] + EPS_BN);
        unsigned short h[8];
#pragma unroll
        for (int j = 0; j < 8; j++) {
            int k = 32 * kh + 8 * q + j;
            h[j] = f2bf(att_W[n * DD + k] * s);
        }
#pragma unroll
        for (int m = 0; m < 4; m++)
            wsu[OFF_ATTFRAG + (size_t)idx * 4 + m] = (u32)h[2 * m] | ((u32)h[2 * m + 1] << 16);
    } else if (i < 8768) {
        int f = i - 8704;
        float s = g2[f] * rsqrtf(v2[f] + EPS_BN);
        ws[OFF_ATTB + f] = att_b[f] * s + b2v[f] - m2[f] * s;
    } else if (i < 21056) {
        int j = i - 8768;
        int d = j / 192, t = j % 192;
        ws[OFF_WIHT + j] = Wih[t * DD + d];
    } else if (i < 33344) {
        int j = i - 21056;
        int d = j / 192, t = j % 192;
        ws[OFF_WHHT + j] = Whh[t * DD + d];
    } else if (i < 43344) {
        // salign[a] = dot(atom[a], alignW[0:64])
        int a = i - 33344;
        const float4* ar = (const float4*)(atom + (size_t)a * DD);
        const float4* aw = (const float4*)alignW;
        float s = 0.f;
#pragma unroll
        for (int qq = 0; qq < 16; qq++) {
            float4 x = ar[qq], w = aw[qq];
            s += x.x * w.x + x.y * w.y + x.z * w.z + x.w * w.w;
        }
        ws[OFF_SALIGN + a] = s;
    } else {
        size_t z = i - 43344;
        if (z < (size_t)N_ATOM + (size_t)N_ATOM * DD) ws[OFF_DENOM + z] = 0.f;
    }
}

// ---------- kernel 1: transposed-MFMA edge pipeline, 4-way d-split ----------
// 256 threads = 4 waves; 32 edges/block (1250 blocks); wave h owns d-quarter.
// r13 main loop (constant-offset loads). Phase B: waves 0/1 GEMM2, wave 2 does
// ALL 32 scores in parallel (lane e = edge e full-row dot via ds_read_b128,
// single shfl_xor(32) to merge the two partial buffers) -- replaces 96
// dependent shuffles per wave with 1.
__global__ __launch_bounds__(256, 4) void edge_kernel(
    const float* atom, const int* bidx, const float* bond,
    const float* alignW, const float* alignb,
    const float* ws, float* denom, float* ctx) {
    __shared__ float s_bond[32][BOND_DIM];
    __shared__ float s_anbr[32][65];
    __shared__ __align__(16) float s_nbp[2][32][68];   // 68: rows 16B-aligned for b128
    __shared__ __align__(16) float s_aw2[64];
    __shared__ float s_ex[32];
    __shared__ int   s_tgt[32];

    const int t = threadIdx.x;
    const int lane = t & 63;
    const int h = t >> 6;        // wave = d-quarter
    const int e0 = blockIdx.x * 32;

    // ---- staging ----
    for (int idx = t; idx < 32 * BOND_DIM; idx += 256)
        s_bond[idx / BOND_DIM][idx % BOND_DIM] = bond[(size_t)e0 * BOND_DIM + idx];
    if (t < 32) s_tgt[t] = bidx[2 * (e0 + t)];
    else if (t >= 64 && t < 128) s_aw2[t - 64] = alignW[64 + (t - 64)];
    for (int e = h; e < 32; e += 4) {
        int nbr = bidx[2 * (e0 + e) + 1];
        s_anbr[e][lane] = atom[(size_t)nbr * DD + lane];
    }
    __syncthreads();

    // stationary bond B-fragment: B[k=8*(lane>>5)+j][n=lane&31]
    const int eb = lane & 31;
    const int kb = 8 * (lane >> 5);
    short8 bfrag;
#pragma unroll
    for (int j = 0; j < 8; j++) {
        int k = kb + j;
        unsigned short hh = 0;
        if (k < BOND_DIM) hh = f2bf(s_bond[eb][k]);
        else if (k == BOND_DIM) hh = 0x3F80u;   // 1.0 (bias slot)
        bfrag[j] = (short)hh;
    }

    const int d0 = 16 * h;
    const short8* aw = (const short8*)((const u32*)ws + OFF_AFRAG) + ((size_t)(d0 * 2) * 64 + lane);
    const float16v zero16 = {};
    const float2v zero2 = {0.f, 0.f};
    float2v nb0[8] = {}, nb1[8] = {};

    // full-unroll d-loop: constant-offset loads, compiler-scheduled prefetch (r13 verbatim)
#pragma unroll
    for (int it = 0; it < 16; it++) {
        short8 a0 = aw[(size_t)(2 * it) * 64];
        short8 a1 = aw[(size_t)(2 * it + 1) * 64];
        float av = s_anbr[eb][d0 + it];
        float2v av2 = {av, av};
        float16v enc0 = __builtin_amdgcn_mfma_f32_32x32x16_bf16(a0, bfrag, zero16, 0, 0, 0);
        float16v enc1 = __builtin_amdgcn_mfma_f32_32x32x16_bf16(a1, bfrag, zero16, 0, 0, 0);
#pragma unroll
        for (int r = 0; r < 8; r++) {
            float2v e0v = {enc0[2 * r], enc0[2 * r + 1]};
            float2v e1v = {enc1[2 * r], enc1[2 * r + 1]};
            e0v = __builtin_elementwise_max(e0v, zero2);
            e1v = __builtin_elementwise_max(e1v, zero2);
            nb0[r] += av2 * e0v;    // contracts to v_pk_fma_f32
            nb1[r] += av2 * e1v;
        }
    }

    // partial nb reduction: waves 0,1 write buffers; waves 2,3 add in place.
    // element e=2r,2r+1 -> f = (e&3)+8*(e>>2)+fro (m74/m101 layout)
    const int fro = 4 * (lane >> 5);
    if (h < 2) {
#pragma unroll
        for (int r = 0; r < 8; r++) {
            int e = 2 * r;
            int f = (e & 3) + 8 * (e >> 2) + fro;
            s_nbp[h][eb][f] = nb0[r].x;
            s_nbp[h][eb][f + 1] = nb0[r].y;
            s_nbp[h][eb][32 + f] = nb1[r].x;
            s_nbp[h][eb][32 + f + 1] = nb1[r].y;
        }
    }
    __syncthreads();
    if (h >= 2) {
#pragma unroll
        for (int r = 0; r < 8; r++) {
            int e = 2 * r;
            int f = (e & 3) + 8 * (e >> 2) + fro;
            s_nbp[h - 2][eb][f] += nb0[r].x;
            s_nbp[h - 2][eb][f + 1] += nb0[r].y;
            s_nbp[h - 2][eb][32 + f] += nb1[r].x;
            s_nbp[h - 2][eb][32 + f + 1] += nb1[r].y;
        }
    }
    __syncthreads();

    // ---- phase B ----
    const int es = (h & 1) * 16;
    const int q = lane >> 4;
    const int r16 = lane & 15;
    float4v att[4];

    if (h < 2) {
        // GEMM2: atend = nb @ attWT (16x16x32, round-8-verified layouts)
        // na[kh][j] = nb[es+r16][32kh+8q+j], vectorized as float4 pairs
        short8 na[2];
        const float4* r0 = (const float4*)&s_nbp[0][es + r16][0];
        const float4* r1 = (const float4*)&s_nbp[1][es + r16][0];
#pragma unroll
        for (int kh = 0; kh < 2; kh++) {
            int c0 = 8 * kh + 2 * q;
            float4 x0 = r0[c0], x1 = r1[c0];
            float4 y0 = r0[c0 + 1], y1 = r1[c0 + 1];
            na[kh][0] = (short)f2bf(x0.x + x1.x);
            na[kh][1] = (short)f2bf(x0.y + x1.y);
            na[kh][2] = (short)f2bf(x0.z + x1.z);
            na[kh][3] = (short)f2bf(x0.w + x1.w);
            na[kh][4] = (short)f2bf(y0.x + y1.x);
            na[kh][5] = (short)f2bf(y0.y + y1.y);
            na[kh][6] = (short)f2bf(y0.z + y1.z);
            na[kh][7] = (short)f2bf(y0.w + y1.w);
        }
        const short8* battfrag = (const short8*)((const u32*)ws + OFF_ATTFRAG);
        const float4v zero4 = {0.f, 0.f, 0.f, 0.f};
#pragma unroll
        for (int fc = 0; fc < 4; fc++) {
            att[fc] = __builtin_amdgcn_mfma_f32_16x16x32_bf16(na[0], battfrag[(fc * 2 + 0) * 64 + lane], zero4, 0, 0, 0);
            att[fc] = __builtin_amdgcn_mfma_f32_16x16x32_bf16(na[1], battfrag[(fc * 2 + 1) * 64 + lane], att[fc], 0, 0, 0);
            float ab = ws[OFF_ATTB + fc * 16 + r16];
#pragma unroll
            for (int r = 0; r < 4; r++) att[fc][r] += ab;
        }
    } else if (h == 2) {
        // all 32 scores in parallel: lane eb handles edge eb's partial-buffer (lane>>5)
        const float4* row = (const float4*)&s_nbp[lane >> 5][eb][0];
        const float4* w4 = (const float4*)s_aw2;
        float dot = 0.f;
#pragma unroll
        for (int c = 0; c < 16; c++) {
            float4 x = row[c], w = w4[c];
            dot += x.x * w.x + x.y * w.y + x.z * w.z + x.w * w.w;
        }
        dot += __shfl_xor(dot, 32);   // merge buffer 0 + buffer 1 halves
        if (lane < 32) {
            int tgt = s_tgt[eb];
            float sc = ws[OFF_SALIGN + tgt] + dot + alignb[0];
            sc = sc > 0.f ? sc : 0.01f * sc;   // leaky_relu slope 0.01
            float ex = expf(sc);               // no max-shift: ratio identity, scores O(1)
            s_ex[eb] = ex;
            atomicAdd(&denom[tgt], ex);
        }
    }
    __syncthreads();

    if (h < 2) {
        // ctx segment-sum atomics (C-layout: e = es+4q+r, f = fc*16+r16)
#pragma unroll
        for (int r = 0; r < 4; r++) {
            int le = es + 4 * q + r;
            float exr = s_ex[le];
            int tg = s_tgt[le];
#pragma unroll
            for (int fc = 0; fc < 4; fc++)
                atomicAdd(&ctx[(size_t)tg * DD + fc * 16 + r16], exr * att[fc][r]);
        }
    }
}

// ---------- kernel 2: context finalize (elu) + GRU cell, transposed weights ----------
__global__ __launch_bounds__(192) void gru_kernel(
    const float* atom, const float* ws, const float* denom, const float* ctx,
    const float* bih, const float* bhh, float* out) {
    __shared__ float sctx[GA][DD];
    __shared__ float satom[GA][DD];
    __shared__ float sgi[GA][192];
    __shared__ float sgh[GA][192];
    const int a0 = blockIdx.x * GA;
    const int t = threadIdx.x;

    for (int idx = t; idx < GA * DD; idx += 192) {
        int a = idx >> 6, f = idx & 63;
        float c = ctx[(size_t)(a0 + a) * DD + f] / (denom[a0 + a] + EPS_SM);
        sctx[a][f] = c > 0.f ? c : expm1f(c);  // elu
        satom[a][f] = atom[(size_t)(a0 + a) * DD + f];
    }
    __syncthreads();

    const float* wiht = ws + OFF_WIHT;
    const float* whht = ws + OFF_WHHT;
    float gi[GA], gh[GA];
    const float bi = bih[t], bh = bhh[t];
#pragma unroll
    for (int a = 0; a < GA; a++) { gi[a] = bi; gh[a] = bh; }
#pragma unroll 4
    for (int d = 0; d < DD; d++) {
        float wi = wiht[d * 192 + t];
        float wh = whht[d * 192 + t];
#pragma unroll
        for (int a = 0; a < GA; a++) {
            gi[a] = fmaf(wi, sctx[a][d], gi[a]);
            gh[a] = fmaf(wh, satom[a][d], gh[a]);
        }
    }
#pragma unroll
    for (int a = 0; a < GA; a++) { sgi[a][t] = gi[a]; sgh[a][t] = gh[a]; }
    __syncthreads();

    for (int idx = t; idx < GA * DD; idx += 192) {
        int a = idx >> 6, f = idx & 63;
        float r = 1.f / (1.f + expf(-(sgi[a][f] + sgh[a][f])));
        float z = 1.f / (1.f + expf(-(sgi[a][64 + f] + sgh[a][64 + f])));
        float n = tanhf(sgi[a][128 + f] + r * sgh[a][128 + f]);
        out[(size_t)(a0 + a) * DD + f] = (1.f - z) * n + z * satom[a][f];
    }
}

extern "C" void kernel_launch(void* const* d_in, const int* in_sizes, int n_in,
                              void* d_out, int out_size, void* d_ws, size_t ws_size,
                              hipStream_t stream) {
    const float* atom   = (const float*)d_in[0];
    const int*   bidx   = (const int*)d_in[1];
    const float* bond   = (const float*)d_in[2];
    const float* enc_W  = (const float*)d_in[3];
    const float* enc_b  = (const float*)d_in[4];
    const float* bn1_g  = (const float*)d_in[5];
    const float* bn1_b  = (const float*)d_in[6];
    const float* bn1_m  = (const float*)d_in[7];
    const float* bn1_v  = (const float*)d_in[8];
    const float* alignW = (const float*)d_in[9];
    const float* alignb = (const float*)d_in[10];
    const float* att_W  = (const float*)d_in[11];
    const float* att_b  = (const float*)d_in[12];
    const float* bn2_g  = (const float*)d_in[13];
    const float* bn2_b  = (const float*)d_in[14];
    const float* bn2_m  = (const float*)d_in[15];
    const float* bn2_v  = (const float*)d_in[16];
    const float* gWih   = (const float*)d_in[17];
    const float* gWhh   = (const float*)d_in[18];
    const float* gbih   = (const float*)d_in[19];
    const float* gbhh   = (const float*)d_in[20];

    float* ws  = (float*)d_ws;
    float* out = (float*)d_out;

    fold_kernel<<<2709, 256, 0, stream>>>(atom, alignW,
                                          enc_W, enc_b, bn1_g, bn1_b, bn1_m, bn1_v,
                                          att_W, att_b, bn2_g, bn2_b, bn2_m, bn2_v,
                                          gWih, gWhh, ws);

    edge_kernel<<<N_EDGE / 32, 256, 0, stream>>>(
        atom, bidx, bond, alignW, alignb, ws,
        ws + OFF_DENOM, ws + OFF_CTX);

    gru_kernel<<<N_ATOM / GA, 192, 0, stream>>>(atom, ws, ws + OFF_DENOM, ws + OFF_CTX,
                                                gbih, gbhh, out);
}